// Round 5
// baseline (504.884 us; speedup 1.0000x reference)
//
#include <hip/hip_runtime.h>

// MultiHeadAttention (B=2, L=2048, C=256, H=W=4, NH=8, DH=32)
// R5: launch-fused prep (q/k/v in one kernel; Xq/Xk alias dead P_bf), fused
//     q/k projections (z=2 grid), norm_kernel removed -> tiny inv_kernel +
//     ctx emits attn fp32 in-loop (by==0 blocks) from the staged LDS P tile.
//
// Workspace (shorts):
//   X2    @ 0           : 16,777,216   (V prep, hw-major; fallback scratch)
//   q_s   @ 16,777,216  : 16,777,216   [bh][l][512]
//   k_s   @ 33,554,432  : 16,777,216
//   v_t   @ 50,331,648  : 16,777,216   [bh][dd][l]
//   Wbf   @ 67,108,864  : 196,608
//   P_bf  @ 67,305,472  : 67,108,864   (prologue: Xq @ +0, Xk @ +16,777,216)
//   part  @ 134,414,336 : 2,097,152    (1,048,576 fp32 [row][32])
//   inv   @ 136,511,488 : 65,536       (32,768 fp32)
// Main path needs ws_size >= 273,154,048 B (falls back to R3-style otherwise).

typedef short s16x8 __attribute__((ext_vector_type(8)));
typedef float f32x4 __attribute__((ext_vector_type(4)));

__device__ __forceinline__ unsigned short f2bf(float f) {
  union { float f; unsigned int u; } v; v.f = f;
  return (unsigned short)((v.u + 0x7FFFu + ((v.u >> 16) & 1u)) >> 16);  // RNE
}
__device__ __forceinline__ float bf2f(unsigned short h) {
  union { unsigned int u; float f; } v; v.u = ((unsigned int)h) << 16;
  return v.f;
}

// async global->LDS, 16B per lane; lds base wave-uniform (HW adds lane*16)
__device__ __forceinline__ void async_copy16(const unsigned short* g, unsigned short* l) {
  __builtin_amdgcn_global_load_lds((const __attribute__((address_space(1))) void*)g,
                                   (__attribute__((address_space(3))) void*)l, 16, 0, 0);
}

// ---------------- prep_all: q/k -> X[(b,l,hw)][c]; v -> X2[(b,hw,l)][c] ----------------
__global__ void __launch_bounds__(256) prep_all_kernel(const float* __restrict__ qs,
                                                       const float* __restrict__ ks,
                                                       const float* __restrict__ vs,
                                                       unsigned short* __restrict__ Xq,
                                                       unsigned short* __restrict__ Xk,
                                                       unsigned short* __restrict__ X2) {
  __shared__ float ld[256 * 17];
  const int bl = blockIdx.x;
  const int z = blockIdx.y;
  const int t = threadIdx.x;
  const float* s = (z == 0 ? qs : (z == 1 ? ks : vs)) + (size_t)bl * 4096;
#pragma unroll
  for (int i = 0; i < 4; ++i) {
    int flat = i * 1024 + t * 4;
    float4 v = *(const float4*)(s + flat);
    int c = flat >> 4, hw = flat & 15;
    float* p = &ld[c * 17 + hw];
    p[0] = v.x; p[1] = v.y; p[2] = v.z; p[3] = v.w;
  }
  __syncthreads();
  if (z < 2) {
    unsigned short* d = (z == 0 ? Xq : Xk) + (size_t)bl * 4096;
#pragma unroll
    for (int hw = 0; hw < 16; ++hw)
      d[hw * 256 + t] = f2bf(ld[t * 17 + hw]);
  } else {
    const int b = bl >> 11, l = bl & 2047;
#pragma unroll
    for (int hw = 0; hw < 16; ++hw)
      X2[((size_t)(b * 16 + hw) * 2048 + l) * 256 + t] = f2bf(ld[t * 17 + hw]);
  }
}

// (fallback) single-input prep
__global__ void __launch_bounds__(256) prep_x_kernel(const float* __restrict__ src,
                                                     unsigned short* __restrict__ dst) {
  __shared__ float ld[256 * 17];
  const int bl = blockIdx.x;
  const int t = threadIdx.x;
  const float* s = src + (size_t)bl * 4096;
#pragma unroll
  for (int i = 0; i < 4; ++i) {
    int flat = i * 1024 + t * 4;
    float4 v = *(const float4*)(s + flat);
    int c = flat >> 4, hw = flat & 15;
    float* p = &ld[c * 17 + hw];
    p[0] = v.x; p[1] = v.y; p[2] = v.z; p[3] = v.w;
  }
  __syncthreads();
  unsigned short* d = dst + (size_t)bl * 4096;
#pragma unroll
  for (int hw = 0; hw < 16; ++hw)
    d[hw * 256 + t] = f2bf(ld[t * 17 + hw]);
}

__global__ void __launch_bounds__(256) prep_w_kernel(const float* __restrict__ a,
                                                     const float* __restrict__ b,
                                                     const float* __restrict__ c,
                                                     unsigned short* __restrict__ dst) {
  int i = blockIdx.x * 256 + threadIdx.x;
  const float* s = (i < 65536) ? a : ((i < 131072) ? b : c);
  dst[i] = f2bf(s[i & 65535]);
}

// ---------------- shared async GEMM core: C(128x128) += A(128xK) * Bt(128xK)^T ----------------
__device__ __forceinline__ void gemm_core_async(const unsigned short* __restrict__ Ag, int ldA,
                                                const unsigned short* __restrict__ Bg, int ldB,
                                                int K, unsigned short* As, unsigned short* Bs,
                                                f32x4 acc[4][4]) {
  const int tid = threadIdx.x;
  const int lane = tid & 63;
  const int w = tid >> 6;
  const int wr = (w >> 1) * 64, wc = (w & 1) * 64;
  const int r = lane >> 2, kk = (lane & 3) * 8;
  for (int k0 = 0; k0 < K; k0 += 32) {
#pragma unroll
    for (int i = 0; i < 2; ++i) {
      const int row0 = w * 32 + i * 16;
      async_copy16(Ag + (size_t)(row0 + r) * ldA + k0 + kk, As + row0 * 32);
      async_copy16(Bg + (size_t)(row0 + r) * ldB + k0 + kk, Bs + row0 * 32);
    }
    __syncthreads();
    s16x8 af[4], bfv[4];
#pragma unroll
    for (int m = 0; m < 4; ++m)
      af[m] = *(const s16x8*)(As + (wr + m * 16 + (lane & 15)) * 32 + (lane >> 4) * 8);
#pragma unroll
    for (int n = 0; n < 4; ++n)
      bfv[n] = *(const s16x8*)(Bs + (wc + n * 16 + (lane & 15)) * 32 + (lane >> 4) * 8);
#pragma unroll
    for (int m = 0; m < 4; ++m)
#pragma unroll
      for (int n = 0; n < 4; ++n)
        acc[m][n] = __builtin_amdgcn_mfma_f32_16x16x32_bf16(af[m], bfv[n], acc[m][n], 0, 0, 0);
    __syncthreads();
  }
}

#define ACC_INIT(acc)                         \
  {                                           \
    const f32x4 z_ = {0.f, 0.f, 0.f, 0.f};    \
    _Pragma("unroll")                         \
    for (int m_ = 0; m_ < 4; ++m_)            \
      _Pragma("unroll")                       \
      for (int n_ = 0; n_ < 4; ++n_) acc[m_][n_] = z_; \
  }

// ---------------- q/k projection (fused z): X(65536x256) * W^T -> [bh][l][512] ----------------
__global__ void __launch_bounds__(256) gemm_proj_qk_kernel(const unsigned short* __restrict__ Xq,
                                                           const unsigned short* __restrict__ Xk,
                                                           const unsigned short* __restrict__ Wbf,
                                                           unsigned short* __restrict__ q_s,
                                                           unsigned short* __restrict__ k_s) {
  __shared__ unsigned short As[4096], Bs[4096];
  f32x4 acc[4][4];
  ACC_INIT(acc);
  const int z = blockIdx.z;
  const unsigned short* X = z ? Xk : Xq;
  const unsigned short* W = Wbf + z * 65536;
  unsigned short* out = z ? k_s : q_s;
  gemm_core_async(X + (size_t)blockIdx.x * 128 * 256, 256,
                  W + (size_t)blockIdx.y * 128 * 256, 256, 256, As, Bs, acc);
  const int tid = threadIdx.x, lane = tid & 63, w = tid >> 6;
  const int wr = (w >> 1) * 64, wc = (w & 1) * 64;
  const int R0 = blockIdx.x * 128 + wr + ((lane >> 4) << 2);
  const int C0 = blockIdx.y * 128 + wc + (lane & 15);
#pragma unroll
  for (int m = 0; m < 4; ++m)
#pragma unroll
    for (int n = 0; n < 4; ++n)
#pragma unroll
      for (int r = 0; r < 4; ++r) {
        int R = R0 + m * 16 + r;          // p = (b*L+l)*16 + hw
        int o = C0 + n * 16;
        int bl = R >> 4, hw = R & 15;
        int b = bl >> 11, l = bl & 2047;
        int head = o >> 5, d = o & 31;
        out[((size_t)(head * 2 + b) * 2048 + l) * 512 + d * 16 + hw] = f2bf(acc[m][n][r]);
      }
}

// (fallback) single projection
__global__ void __launch_bounds__(256) gemm_proj_kernel(const unsigned short* __restrict__ X,
                                                        const unsigned short* __restrict__ W,
                                                        unsigned short* __restrict__ out) {
  __shared__ unsigned short As[4096], Bs[4096];
  f32x4 acc[4][4];
  ACC_INIT(acc);
  gemm_core_async(X + (size_t)blockIdx.x * 128 * 256, 256,
                  W + (size_t)blockIdx.y * 128 * 256, 256, 256, As, Bs, acc);
  const int tid = threadIdx.x, lane = tid & 63, w = tid >> 6;
  const int wr = (w >> 1) * 64, wc = (w & 1) * 64;
  const int R0 = blockIdx.x * 128 + wr + ((lane >> 4) << 2);
  const int C0 = blockIdx.y * 128 + wc + (lane & 15);
#pragma unroll
  for (int m = 0; m < 4; ++m)
#pragma unroll
    for (int n = 0; n < 4; ++n)
#pragma unroll
      for (int r = 0; r < 4; ++r) {
        int R = R0 + m * 16 + r;
        int o = C0 + n * 16;
        int bl = R >> 4, hw = R & 15;
        int b = bl >> 11, l = bl & 2047;
        int head = o >> 5, d = o & 31;
        out[((size_t)(head * 2 + b) * 2048 + l) * 512 + d * 16 + hw] = f2bf(acc[m][n][r]);
      }
}

// ---------------- V projection (transposed): W x X2^T -> v_t[bh][dd][l] ----------------
__global__ void __launch_bounds__(256) gemm_proj_vt_kernel(const unsigned short* __restrict__ W,
                                                           const unsigned short* __restrict__ X2,
                                                           unsigned short* __restrict__ vt) {
  __shared__ unsigned short As[4096], Bs[4096];
  f32x4 acc[4][4];
  ACC_INIT(acc);
  gemm_core_async(W + (size_t)blockIdx.x * 128 * 256, 256,
                  X2 + (size_t)blockIdx.y * 128 * 256, 256, 256, As, Bs, acc);
  const int tid = threadIdx.x, lane = tid & 63, w = tid >> 6;
  const int wr = (w >> 1) * 64, wc = (w & 1) * 64;
  const int R0 = blockIdx.x * 128 + wr + ((lane >> 4) << 2);   // o rows
  const int C0 = blockIdx.y * 128 + wc + (lane & 15);          // p' cols
#pragma unroll
  for (int m = 0; m < 4; ++m)
#pragma unroll
    for (int n = 0; n < 4; ++n)
#pragma unroll
      for (int r = 0; r < 4; ++r) {
        int o = R0 + m * 16 + r;          // channel: head*32 + d
        int p = C0 + n * 16;              // (b*16+hw)*2048 + l
        int head = o >> 5, d = o & 31;
        int b = p >> 15, hw = (p >> 11) & 15, l = p & 2047;
        vt[((size_t)((head * 2 + b) * 512) + d * 16 + hw) * 2048 + l] = f2bf(acc[m][n][r]);
      }
}

// ---------------- score: q*k^T; FUSED: P_bf=bf16(exp(s)) + partial row sums ----------------
template <int FUSED>
__global__ void __launch_bounds__(256) gemm_score_kernel(const unsigned short* __restrict__ q,
                                                         const unsigned short* __restrict__ k,
                                                         float* __restrict__ attn,
                                                         unsigned short* __restrict__ pbf,
                                                         float* __restrict__ partial) {
  __shared__ unsigned short As[4096], Bs[4096];
  f32x4 acc[4][4];
  ACC_INIT(acc);
  const int bh = blockIdx.z;
  gemm_core_async(q + ((size_t)bh * 2048 + blockIdx.x * 128) * 512, 512,
                  k + ((size_t)bh * 2048 + blockIdx.y * 128) * 512, 512, 512, As, Bs, acc);
  const int tid = threadIdx.x, lane = tid & 63, w = tid >> 6;
  const int wr = (w >> 1) * 64, wc = (w & 1) * 64;
  const float scale = 0.17677669529663687f;  // 1/sqrt(32)
  const int R0 = blockIdx.x * 128 + wr + ((lane >> 4) << 2);
  const int C0 = blockIdx.y * 128 + wc + (lane & 15);
  if (!FUSED) {
    float* O = attn + (size_t)bh * 4194304;
#pragma unroll
    for (int m = 0; m < 4; ++m)
#pragma unroll
      for (int n = 0; n < 4; ++n)
#pragma unroll
        for (int r = 0; r < 4; ++r)
          O[(size_t)(R0 + m * 16 + r) * 2048 + (C0 + n * 16)] = acc[m][n][r] * scale;
  } else {
#pragma unroll
    for (int m = 0; m < 4; ++m)
#pragma unroll
      for (int n = 0; n < 4; ++n)
#pragma unroll
        for (int r = 0; r < 4; ++r)
          acc[m][n][r] = __expf(acc[m][n][r] * scale);
    unsigned short* P = pbf + (size_t)bh * 4194304;
#pragma unroll
    for (int m = 0; m < 4; ++m)
#pragma unroll
      for (int n = 0; n < 4; ++n)
#pragma unroll
        for (int r = 0; r < 4; ++r)
          P[(size_t)(R0 + m * 16 + r) * 2048 + (C0 + n * 16)] = f2bf(acc[m][n][r]);
    const int chunk = blockIdx.y * 2 + (w & 1);
#pragma unroll
    for (int m = 0; m < 4; ++m)
#pragma unroll
      for (int r = 0; r < 4; ++r) {
        float s = (acc[m][0][r] + acc[m][1][r]) + (acc[m][2][r] + acc[m][3][r]);
        s += __shfl_xor(s, 1); s += __shfl_xor(s, 2);
        s += __shfl_xor(s, 4); s += __shfl_xor(s, 8);
        if ((lane & 15) == 0) {
          int rloc = wr + ((lane >> 4) << 2) + m * 16 + r;
          partial[((size_t)bh * 2048 + blockIdx.x * 128 + rloc) * 32 + chunk] = s;
        }
      }
  }
}

// ---------------- inv: rowsum partials -> inv[row] ----------------
__global__ void __launch_bounds__(256) inv_kernel(const float* __restrict__ partial,
                                                  float* __restrict__ inv_buf) {
  const int t = threadIdx.x;
  const int row = blockIdx.x * 64 + (t >> 2);
  const int q4 = t & 3;
  const float4* p = (const float4*)(partial + (size_t)row * 32 + q4 * 8);
  float4 a = p[0], b = p[1];
  float s = ((a.x + a.y) + (a.z + a.w)) + ((b.x + b.y) + (b.z + b.w));
  s += __shfl_xor(s, 1); s += __shfl_xor(s, 2);
  if (q4 == 0) inv_buf[row] = 1.0f / s;
}

// ---------------- ctx epilogue (shared; optional inv scaling) ----------------
__device__ __forceinline__ void ctx_epilogue(f32x4 acc[4][4], float* __restrict__ outc,
                                             const float* __restrict__ inv_buf,
                                             int bh, int bx, int by) {
  const int tid = threadIdx.x, lane = tid & 63, w = tid >> 6;
  const int wr = (w >> 1) * 64, wc = (w & 1) * 64;
  const int b = bh & 1, head = bh >> 1;
  const int R0 = bx * 128 + wr + ((lane >> 4) << 2);
  const int C0 = by * 128 + wc + (lane & 15);
#pragma unroll
  for (int m = 0; m < 4; ++m)
#pragma unroll
    for (int r2 = 0; r2 < 4; ++r2) {
      int R = R0 + m * 16 + r2;
      float sc = inv_buf ? inv_buf[(size_t)bh * 2048 + R] : 1.0f;
#pragma unroll
      for (int n = 0; n < 4; ++n) {
        int dd = C0 + n * 16;
        int d = dd >> 4, hw = dd & 15;
        outc[((size_t)(b * 2048 + R) * 256 + head * 32 + d) * 16 + hw] = acc[m][n][r2] * sc;
      }
    }
}

// ---------------- context: P_bf * v_t^T (scaled by inv); by==0 blocks emit attn ----------------
__global__ void __launch_bounds__(256) gemm_ctx_fused_kernel(const unsigned short* __restrict__ pbf,
                                                             const unsigned short* __restrict__ vt,
                                                             const float* __restrict__ inv_buf,
                                                             float* __restrict__ attn,
                                                             float* __restrict__ outc) {
  __shared__ unsigned short As[4096], Bs[4096];
  f32x4 acc[4][4];
  ACC_INIT(acc);
  const int tid = threadIdx.x, lane = tid & 63, w = tid >> 6;
  const int wr = (w >> 1) * 64, wc = (w & 1) * 64;
  const int bh = blockIdx.z;
  const unsigned short* Ag = pbf + (size_t)bh * 4194304 + (size_t)blockIdx.x * 128 * 2048;
  const unsigned short* Bg = vt + (size_t)bh * 1048576 + (size_t)blockIdx.y * 128 * 2048;
  const int r = lane >> 2, kk = (lane & 3) * 8;
  const bool emit = (blockIdx.y == 0);
  // attn-emit mapping: thread t covers row (t>>1), cols (t&1)*16..+16 of the [128][32] tile
  const int erow = tid >> 1, ecol = (tid & 1) * 16;
  float einv = 0.f;
  float* eattn = nullptr;
  if (emit) {
    einv = inv_buf[(size_t)bh * 2048 + blockIdx.x * 128 + erow];
    eattn = attn + (size_t)bh * 4194304 + (size_t)(blockIdx.x * 128 + erow) * 2048 + ecol;
  }
  for (int k0 = 0; k0 < 2048; k0 += 32) {
#pragma unroll
    for (int i = 0; i < 2; ++i) {
      const int row0 = w * 32 + i * 16;
      async_copy16(Ag + (size_t)(row0 + r) * 2048 + k0 + kk, As + row0 * 32);
      async_copy16(Bg + (size_t)(row0 + r) * 2048 + k0 + kk, Bs + row0 * 32);
    }
    __syncthreads();
    if (emit) {  // write attn fp32 from staged P tile
      s16x8 h0 = *(const s16x8*)(As + erow * 32 + ecol);
      s16x8 h1 = *(const s16x8*)(As + erow * 32 + ecol + 8);
      float o[16];
#pragma unroll
      for (int i = 0; i < 8; ++i) o[i] = bf2f((unsigned short)h0[i]) * einv;
#pragma unroll
      for (int i = 0; i < 8; ++i) o[8 + i] = bf2f((unsigned short)h1[i]) * einv;
      float* ep = eattn + k0;
      *(float4*)(ep)      = *(float4*)&o[0];
      *(float4*)(ep + 4)  = *(float4*)&o[4];
      *(float4*)(ep + 8)  = *(float4*)&o[8];
      *(float4*)(ep + 12) = *(float4*)&o[12];
    }
    s16x8 af[4], bfv[4];
#pragma unroll
    for (int m = 0; m < 4; ++m)
      af[m] = *(const s16x8*)(As + (wr + m * 16 + (lane & 15)) * 32 + (lane >> 4) * 8);
#pragma unroll
    for (int n = 0; n < 4; ++n)
      bfv[n] = *(const s16x8*)(Bs + (wc + n * 16 + (lane & 15)) * 32 + (lane >> 4) * 8);
#pragma unroll
    for (int m = 0; m < 4; ++m)
#pragma unroll
      for (int n = 0; n < 4; ++n)
        acc[m][n] = __builtin_amdgcn_mfma_f32_16x16x32_bf16(af[m], bfv[n], acc[m][n], 0, 0, 0);
    __syncthreads();
  }
  ctx_epilogue(acc, outc, inv_buf, bh, blockIdx.x, blockIdx.y);
}

// ---------------- fallback kernels (R3 path) ----------------
__global__ void __launch_bounds__(256) softmax_kernel(float* __restrict__ attn) {
  __shared__ float red[4];
  float* p = attn + (size_t)blockIdx.x * 2048;
  const int t = threadIdx.x;
  float4 v0 = *(const float4*)(p + t * 8);
  float4 v1 = *(const float4*)(p + t * 8 + 4);
  float mx = fmaxf(fmaxf(fmaxf(v0.x, v0.y), fmaxf(v0.z, v0.w)),
                   fmaxf(fmaxf(v1.x, v1.y), fmaxf(v1.z, v1.w)));
#pragma unroll
  for (int off = 32; off; off >>= 1) mx = fmaxf(mx, __shfl_xor(mx, off));
  if ((t & 63) == 0) red[t >> 6] = mx;
  __syncthreads();
  mx = fmaxf(fmaxf(red[0], red[1]), fmaxf(red[2], red[3]));
  __syncthreads();
  float e[8];
  e[0] = __expf(v0.x - mx); e[1] = __expf(v0.y - mx);
  e[2] = __expf(v0.z - mx); e[3] = __expf(v0.w - mx);
  e[4] = __expf(v1.x - mx); e[5] = __expf(v1.y - mx);
  e[6] = __expf(v1.z - mx); e[7] = __expf(v1.w - mx);
  float s = ((e[0] + e[1]) + (e[2] + e[3])) + ((e[4] + e[5]) + (e[6] + e[7]));
#pragma unroll
  for (int off = 32; off; off >>= 1) s += __shfl_xor(s, off);
  if ((t & 63) == 0) red[t >> 6] = s;
  __syncthreads();
  s = red[0] + red[1] + red[2] + red[3];
  const float inv = 1.0f / s;
  float4 o0 = {e[0] * inv, e[1] * inv, e[2] * inv, e[3] * inv};
  float4 o1 = {e[4] * inv, e[5] * inv, e[6] * inv, e[7] * inv};
  *(float4*)(p + t * 8) = o0;
  *(float4*)(p + t * 8 + 4) = o1;
}

__global__ void __launch_bounds__(256) transpose_v_kernel(const unsigned short* __restrict__ vs,
                                                          unsigned short* __restrict__ vt) {
  __shared__ unsigned short tile[64][65];
  const int bh = blockIdx.z;
  const int j0 = blockIdx.x * 64, d0 = blockIdx.y * 64;
  const unsigned short* src = vs + (size_t)bh * 2048 * 512;
  unsigned short* dst = vt + (size_t)bh * 512 * 2048;
  const int t = threadIdx.x;
#pragma unroll
  for (int i = 0; i < 16; ++i) {
    int e = t * 16 + i;
    int r = e >> 6, c = e & 63;
    tile[r][c] = src[(size_t)(j0 + r) * 512 + d0 + c];
  }
  __syncthreads();
#pragma unroll
  for (int i = 0; i < 16; ++i) {
    int e = t * 16 + i;
    int r = e >> 6, c = e & 63;
    dst[(size_t)(d0 + r) * 2048 + j0 + c] = tile[c][r];
  }
}

__global__ void __launch_bounds__(256) gemm_ctx_f32_kernel(const float* __restrict__ attn,
                                                           const unsigned short* __restrict__ vt,
                                                           float* __restrict__ outc) {
  __shared__ unsigned short As[4096], Bs[4096];
  f32x4 acc[4][4];
  ACC_INIT(acc);
  const int tid = threadIdx.x, lane = tid & 63, w = tid >> 6;
  const int wr = (w >> 1) * 64, wc = (w & 1) * 64;
  const int bh = blockIdx.z;
  const float* Ag = attn + (size_t)bh * 4194304 + (size_t)blockIdx.x * 128 * 2048;
  const unsigned short* Bg = vt + (size_t)bh * 1048576 + (size_t)blockIdx.y * 128 * 2048;
  const int r = lane >> 2, kk = (lane & 3) * 8;
  const int arow = tid >> 1, acol = (tid & 1) * 16;
  for (int k0 = 0; k0 < 2048; k0 += 32) {
#pragma unroll
    for (int i = 0; i < 2; ++i) {
      const int row0 = w * 32 + i * 16;
      async_copy16(Bg + (size_t)(row0 + r) * 2048 + k0 + kk, Bs + row0 * 32);
    }
    {
      const float* sp = Ag + (size_t)arow * 2048 + k0 + acol;
      float4 f0 = *(const float4*)(sp);
      float4 f1 = *(const float4*)(sp + 4);
      float4 f2 = *(const float4*)(sp + 8);
      float4 f3 = *(const float4*)(sp + 12);
      s16x8 h0, h1;
      h0[0] = (short)f2bf(f0.x); h0[1] = (short)f2bf(f0.y);
      h0[2] = (short)f2bf(f0.z); h0[3] = (short)f2bf(f0.w);
      h0[4] = (short)f2bf(f1.x); h0[5] = (short)f2bf(f1.y);
      h0[6] = (short)f2bf(f1.z); h0[7] = (short)f2bf(f1.w);
      h1[0] = (short)f2bf(f2.x); h1[1] = (short)f2bf(f2.y);
      h1[2] = (short)f2bf(f2.z); h1[3] = (short)f2bf(f2.w);
      h1[4] = (short)f2bf(f3.x); h1[5] = (short)f2bf(f3.y);
      h1[6] = (short)f2bf(f3.z); h1[7] = (short)f2bf(f3.w);
      *(s16x8*)(As + arow * 32 + acol) = h0;
      *(s16x8*)(As + arow * 32 + acol + 8) = h1;
    }
    __syncthreads();
    s16x8 af[4], bfv[4];
#pragma unroll
    for (int m = 0; m < 4; ++m)
      af[m] = *(const s16x8*)(As + (wr + m * 16 + (lane & 15)) * 32 + (lane >> 4) * 8);
#pragma unroll
    for (int n = 0; n < 4; ++n)
      bfv[n] = *(const s16x8*)(Bs + (wc + n * 16 + (lane & 15)) * 32 + (lane >> 4) * 8);
#pragma unroll
    for (int m = 0; m < 4; ++m)
#pragma unroll
      for (int n = 0; n < 4; ++n)
        acc[m][n] = __builtin_amdgcn_mfma_f32_16x16x32_bf16(af[m], bfv[n], acc[m][n], 0, 0, 0);
    __syncthreads();
  }
  ctx_epilogue(acc, outc, nullptr, bh, blockIdx.x, blockIdx.y);
}

extern "C" void kernel_launch(void* const* d_in, const int* in_sizes, int n_in,
                              void* d_out, int out_size, void* d_ws, size_t ws_size,
                              hipStream_t stream) {
  const float* query = (const float*)d_in[0];
  const float* key   = (const float*)d_in[1];
  const float* value = (const float*)d_in[2];
  const float* Wq    = (const float*)d_in[3];
  const float* Wk    = (const float*)d_in[4];
  const float* Wv    = (const float*)d_in[5];

  float* out_ctx  = (float*)d_out;
  float* out_attn = (float*)d_out + 16777216;

  unsigned short* X2   = (unsigned short*)d_ws;
  unsigned short* q_s  = X2 + 16777216;
  unsigned short* k_s  = q_s + 16777216;
  unsigned short* v_t  = k_s + 16777216;
  unsigned short* Wbf  = v_t + 16777216;        // 196,608 shorts
  unsigned short* P_bf = Wbf + 196608;          // 67,108,864 shorts
  float* partial = (float*)(P_bf + 67108864);   // 1,048,576 floats
  float* inv_buf = partial + 1048576;           // 32,768 floats

  unsigned short* Xq = P_bf;                    // aliases (dead before score writes P_bf)
  unsigned short* Xk = P_bf + 16777216;

  const bool fused = ws_size >= (size_t)273154048;

  prep_w_kernel<<<768, 256, 0, stream>>>(Wq, Wk, Wv, Wbf);

  if (fused) {
    prep_all_kernel<<<dim3(4096, 3), 256, 0, stream>>>(query, key, value, Xq, Xk, X2);
    gemm_proj_qk_kernel<<<dim3(512, 2, 2), 256, 0, stream>>>(Xq, Xk, Wbf, q_s, k_s);
    gemm_proj_vt_kernel<<<dim3(2, 512), 256, 0, stream>>>(Wbf + 131072, X2, v_t);
    gemm_score_kernel<1><<<dim3(16, 16, 16), 256, 0, stream>>>(q_s, k_s, nullptr, P_bf, partial);
    inv_kernel<<<512, 256, 0, stream>>>(partial, inv_buf);
    gemm_ctx_fused_kernel<<<dim3(16, 4, 16), 256, 0, stream>>>(P_bf, v_t, inv_buf, out_attn, out_ctx);
  } else {
    prep_x_kernel<<<4096, 256, 0, stream>>>(query, X2);
    gemm_proj_kernel<<<dim3(512, 2), 256, 0, stream>>>(X2, Wbf, q_s);
    prep_x_kernel<<<4096, 256, 0, stream>>>(key, X2);
    gemm_proj_kernel<<<dim3(512, 2), 256, 0, stream>>>(X2, Wbf + 65536, k_s);
    prep_x_kernel<<<4096, 256, 0, stream>>>(value, X2);
    gemm_proj_kernel<<<dim3(512, 2), 256, 0, stream>>>(X2, Wbf + 131072, v_t);  // v_s layout
    gemm_score_kernel<0><<<dim3(16, 16, 16), 256, 0, stream>>>(q_s, k_s, out_attn, nullptr, nullptr);
    softmax_kernel<<<32768, 256, 0, stream>>>(out_attn);
    transpose_v_kernel<<<dim3(32, 8, 16), 256, 0, stream>>>(v_t, X2);           // X2 becomes v_t
    gemm_ctx_f32_kernel<<<dim3(16, 4, 16), 256, 0, stream>>>(out_attn, X2, out_ctx);
  }
}

// Round 6
// 416.160 us; speedup vs baseline: 1.2132x; 1.2132x over previous
//
#include <hip/hip_runtime.h>

// MultiHeadAttention (B=2, L=2048, C=256, H=W=4, NH=8, DH=32)
// R6: score & ctx use a 256x256 BK=32 double-buffered pipelined GEMM:
//     counted vmcnt(4) across raw s_barriers (T3/T4), XOR bank swizzle (T2),
//     setprio around MFMA (T5). Prep/proj fusion kept from R5; norm restored
//     from R4 (ctx in-loop attn emission reverted — barrier-drain regression).
//
// Workspace (shorts):
//   X2    @ 0           : 16,777,216   (V prep, hw-major; fallback scratch)
//   q_s   @ 16,777,216  : 16,777,216   [bh][l][512]
//   k_s   @ 33,554,432  : 16,777,216
//   v_t   @ 50,331,648  : 16,777,216   [bh][dd][l]
//   Wbf   @ 67,108,864  : 196,608
//   P_bf  @ 67,305,472  : 67,108,864   (prologue: Xq @ +0, Xk @ +16,777,216)
//   part  @ 134,414,336 : 2,097,152    (1,048,576 fp32 [row][32])
//   inv   @ 136,511,488 : 65,536       (32,768 fp32)
// Main path needs ws_size >= 273,154,048 B (falls back to R3-style otherwise).

typedef short s16x8 __attribute__((ext_vector_type(8)));
typedef float f32x4 __attribute__((ext_vector_type(4)));

__device__ __forceinline__ unsigned short f2bf(float f) {
  union { float f; unsigned int u; } v; v.f = f;
  return (unsigned short)((v.u + 0x7FFFu + ((v.u >> 16) & 1u)) >> 16);  // RNE
}
__device__ __forceinline__ float bf2f(unsigned short h) {
  union { unsigned int u; float f; } v; v.u = ((unsigned int)h) << 16;
  return v.f;
}

// async global->LDS, 16B per lane; lds base wave-uniform (HW adds lane*16)
__device__ __forceinline__ void async_copy16(const unsigned short* g, unsigned short* l) {
  __builtin_amdgcn_global_load_lds((const __attribute__((address_space(1))) void*)g,
                                   (__attribute__((address_space(3))) void*)l, 16, 0, 0);
}

// ================= 256x256 BK=32 pipelined GEMM core =================
// LDS tile layout: [256 rows][4 granules of 8 bf16], physical granule
// pg holds logical granule pg ^ ((row>>1)&3)  (involution; 2-way banks = free).

template <int LD>
__device__ __forceinline__ void stage256(const unsigned short* __restrict__ Xg,
                                         unsigned short* __restrict__ lds_base,
                                         int kt) {
  const int tid = threadIdx.x;
  const int wid = tid >> 6, lane = tid & 63;
  const int prow = lane >> 2, pgran = lane & 3;
  const int lgran = pgran ^ ((prow >> 1) & 3);   // inverse-swizzled source granule
  const int row0 = wid * 32;                     // wave stages rows [row0, row0+32)
#pragma unroll
  for (int i = 0; i < 2; ++i) {
    const int rb = row0 + i * 16;                // 16 rows per gload (64 lanes x 16B = 1KB)
    async_copy16(Xg + (size_t)(rb + prow) * LD + kt * 32 + lgran * 8,
                 lds_base + rb * 32);
  }
}

__device__ __forceinline__ void compute256(const unsigned short* __restrict__ As_,
                                           const unsigned short* __restrict__ Bs_,
                                           f32x4 acc[8][4]) {
  const int tid = threadIdx.x, lane = tid & 63, wid = tid >> 6;
  const int wm = wid >> 2, wn = wid & 3;
  const int rl = lane & 15;
  const int xg = (lane >> 4) ^ ((rl >> 1) & 3);  // swizzled read granule
  const unsigned short* Aw = As_ + (size_t)(wm * 128 + rl) * 32 + xg * 8;
  const unsigned short* Bw = Bs_ + (size_t)(wn * 64 + rl) * 32 + xg * 8;
  s16x8 b[4], a[4];
#pragma unroll
  for (int n = 0; n < 4; ++n) b[n] = *(const s16x8*)(Bw + n * 16 * 32);
#pragma unroll
  for (int m = 0; m < 4; ++m) a[m] = *(const s16x8*)(Aw + m * 16 * 32);
  __builtin_amdgcn_s_setprio(1);
#pragma unroll
  for (int m = 0; m < 4; ++m)
#pragma unroll
    for (int n = 0; n < 4; ++n)
      acc[m][n] = __builtin_amdgcn_mfma_f32_16x16x32_bf16(a[m], b[n], acc[m][n], 0, 0, 0);
  __builtin_amdgcn_s_setprio(0);
#pragma unroll
  for (int m = 0; m < 4; ++m) a[m] = *(const s16x8*)(Aw + (64 + m * 16) * 32);
  __builtin_amdgcn_s_setprio(1);
#pragma unroll
  for (int m = 0; m < 4; ++m)
#pragma unroll
    for (int n = 0; n < 4; ++n)
      acc[4 + m][n] = __builtin_amdgcn_mfma_f32_16x16x32_bf16(a[m], b[n], acc[4 + m][n], 0, 0, 0);
  __builtin_amdgcn_s_setprio(0);
}

template <int LD, int NT>
__device__ __forceinline__ void gemm256_loop(const unsigned short* __restrict__ Ag,
                                             const unsigned short* __restrict__ Bg,
                                             unsigned short (*As)[8192],
                                             unsigned short (*Bs)[8192],
                                             f32x4 acc[8][4]) {
  stage256<LD>(Ag, As[0], 0); stage256<LD>(Bg, Bs[0], 0);   // 4 vmem/thread
  stage256<LD>(Ag, As[1], 1); stage256<LD>(Bg, Bs[1], 1);   // 4 vmem/thread
  for (int kt = 0; kt < NT; ++kt) {
    if (kt < NT - 1) asm volatile("s_waitcnt vmcnt(4)" ::: "memory");  // cur tile landed
    else             asm volatile("s_waitcnt vmcnt(0)" ::: "memory");
    __builtin_amdgcn_s_barrier();
    compute256(As[kt & 1], Bs[kt & 1], acc);
    __builtin_amdgcn_s_barrier();      // all waves done reading buf before restage
    if (kt + 2 < NT) {
      stage256<LD>(Ag, As[kt & 1], kt + 2);
      stage256<LD>(Bg, Bs[kt & 1], kt + 2);
    }
  }
}

#define ACC_INIT8(acc)                        \
  {                                           \
    const f32x4 z_ = {0.f, 0.f, 0.f, 0.f};    \
    _Pragma("unroll")                         \
    for (int m_ = 0; m_ < 8; ++m_)            \
      _Pragma("unroll")                       \
      for (int n_ = 0; n_ < 4; ++n_) acc[m_][n_] = z_; \
  }

// ---------------- score256: q*k^T -> P_bf = bf16(exp(s*scale)) + partial sums ----------------
__global__ void __launch_bounds__(512, 2)
gemm_score256_kernel(const unsigned short* __restrict__ q, const unsigned short* __restrict__ k,
                     unsigned short* __restrict__ pbf, float* __restrict__ partial) {
  __shared__ unsigned short As[2][8192], Bs[2][8192];
  f32x4 acc[8][4];
  ACC_INIT8(acc);
  const int bh = blockIdx.z;
  const unsigned short* Ag = q + ((size_t)bh * 2048 + blockIdx.x * 256) * 512;
  const unsigned short* Bg = k + ((size_t)bh * 2048 + blockIdx.y * 256) * 512;
  gemm256_loop<512, 16>(Ag, Bg, As, Bs, acc);
  const int tid = threadIdx.x, lane = tid & 63, wid = tid >> 6;
  const int wm = wid >> 2, wn = wid & 3;
  const float scale = 0.17677669529663687f;  // 1/sqrt(32)
  const int R0 = blockIdx.x * 256 + wm * 128 + ((lane >> 4) << 2);
  const int C0 = blockIdx.y * 256 + wn * 64 + (lane & 15);
  unsigned short* P = pbf + (size_t)bh * 4194304;
#pragma unroll
  for (int m = 0; m < 8; ++m)
#pragma unroll
    for (int n = 0; n < 4; ++n)
#pragma unroll
      for (int r = 0; r < 4; ++r) {
        float e = __expf(acc[m][n][r] * scale);   // no-max softmax: |s|<~8, safe
        acc[m][n][r] = e;
        P[(size_t)(R0 + m * 16 + r) * 2048 + (C0 + n * 16)] = f2bf(e);
      }
  const int chunk = blockIdx.y * 4 + wn;          // 64-col chunk index (0..31)
#pragma unroll
  for (int m = 0; m < 8; ++m)
#pragma unroll
    for (int r = 0; r < 4; ++r) {
      float s = (acc[m][0][r] + acc[m][1][r]) + (acc[m][2][r] + acc[m][3][r]);
      s += __shfl_xor(s, 1); s += __shfl_xor(s, 2);
      s += __shfl_xor(s, 4); s += __shfl_xor(s, 8);
      if ((lane & 15) == 0)
        partial[((size_t)bh * 2048 + R0 + m * 16 + r) * 32 + chunk] = s;
    }
}

// ---------------- ctx256: P_bf * v_t^T, scaled by inv, scatter to (B,L,C,H,W) ----------------
__global__ void __launch_bounds__(512, 2)
gemm_ctx256_kernel(const unsigned short* __restrict__ pbf, const unsigned short* __restrict__ vt,
                   const float* __restrict__ inv_buf, float* __restrict__ outc) {
  __shared__ unsigned short As[2][8192], Bs[2][8192];
  f32x4 acc[8][4];
  ACC_INIT8(acc);
  const int bh = blockIdx.z;
  const unsigned short* Ag = pbf + (size_t)bh * 4194304 + (size_t)blockIdx.x * 256 * 2048;
  const unsigned short* Bg = vt + (size_t)bh * 1048576 + (size_t)blockIdx.y * 256 * 2048;
  gemm256_loop<2048, 64>(Ag, Bg, As, Bs, acc);
  const int tid = threadIdx.x, lane = tid & 63, wid = tid >> 6;
  const int wm = wid >> 2, wn = wid & 3;
  const int b = bh & 1, head = bh >> 1;
  const int R0 = blockIdx.x * 256 + wm * 128 + ((lane >> 4) << 2);
  const int C0 = blockIdx.y * 256 + wn * 64 + (lane & 15);
#pragma unroll
  for (int m = 0; m < 8; ++m)
#pragma unroll
    for (int r = 0; r < 4; ++r) {
      const int R = R0 + m * 16 + r;
      const float sc = inv_buf[(size_t)bh * 2048 + R];
#pragma unroll
      for (int n = 0; n < 4; ++n) {
        int dd = C0 + n * 16;
        outc[((size_t)(b * 2048 + R) * 256 + head * 32 + (dd >> 4)) * 16 + (dd & 15)] =
            acc[m][n][r] * sc;
      }
    }
}

// ---------------- prep_all: q/k -> X[(b,l,hw)][c]; v -> X2[(b,hw,l)][c] ----------------
__global__ void __launch_bounds__(256) prep_all_kernel(const float* __restrict__ qs,
                                                       const float* __restrict__ ks,
                                                       const float* __restrict__ vs,
                                                       unsigned short* __restrict__ Xq,
                                                       unsigned short* __restrict__ Xk,
                                                       unsigned short* __restrict__ X2) {
  __shared__ float ld[256 * 17];
  const int bl = blockIdx.x;
  const int z = blockIdx.y;
  const int t = threadIdx.x;
  const float* s = (z == 0 ? qs : (z == 1 ? ks : vs)) + (size_t)bl * 4096;
#pragma unroll
  for (int i = 0; i < 4; ++i) {
    int flat = i * 1024 + t * 4;
    float4 v = *(const float4*)(s + flat);
    int c = flat >> 4, hw = flat & 15;
    float* p = &ld[c * 17 + hw];
    p[0] = v.x; p[1] = v.y; p[2] = v.z; p[3] = v.w;
  }
  __syncthreads();
  if (z < 2) {
    unsigned short* d = (z == 0 ? Xq : Xk) + (size_t)bl * 4096;
#pragma unroll
    for (int hw = 0; hw < 16; ++hw)
      d[hw * 256 + t] = f2bf(ld[t * 17 + hw]);
  } else {
    const int b = bl >> 11, l = bl & 2047;
#pragma unroll
    for (int hw = 0; hw < 16; ++hw)
      X2[((size_t)(b * 16 + hw) * 2048 + l) * 256 + t] = f2bf(ld[t * 17 + hw]);
  }
}

// (fallback) single-input prep
__global__ void __launch_bounds__(256) prep_x_kernel(const float* __restrict__ src,
                                                     unsigned short* __restrict__ dst) {
  __shared__ float ld[256 * 17];
  const int bl = blockIdx.x;
  const int t = threadIdx.x;
  const float* s = src + (size_t)bl * 4096;
#pragma unroll
  for (int i = 0; i < 4; ++i) {
    int flat = i * 1024 + t * 4;
    float4 v = *(const float4*)(s + flat);
    int c = flat >> 4, hw = flat & 15;
    float* p = &ld[c * 17 + hw];
    p[0] = v.x; p[1] = v.y; p[2] = v.z; p[3] = v.w;
  }
  __syncthreads();
  unsigned short* d = dst + (size_t)bl * 4096;
#pragma unroll
  for (int hw = 0; hw < 16; ++hw)
    d[hw * 256 + t] = f2bf(ld[t * 17 + hw]);
}

__global__ void __launch_bounds__(256) prep_w_kernel(const float* __restrict__ a,
                                                     const float* __restrict__ b,
                                                     const float* __restrict__ c,
                                                     unsigned short* __restrict__ dst) {
  int i = blockIdx.x * 256 + threadIdx.x;
  const float* s = (i < 65536) ? a : ((i < 131072) ? b : c);
  dst[i] = f2bf(s[i & 65535]);
}

// ---------------- 128^2 async GEMM core (projections + fallback) ----------------
__device__ __forceinline__ void gemm_core_async(const unsigned short* __restrict__ Ag, int ldA,
                                                const unsigned short* __restrict__ Bg, int ldB,
                                                int K, unsigned short* As, unsigned short* Bs,
                                                f32x4 acc[4][4]) {
  const int tid = threadIdx.x;
  const int lane = tid & 63;
  const int w = tid >> 6;
  const int wr = (w >> 1) * 64, wc = (w & 1) * 64;
  const int r = lane >> 2, kk = (lane & 3) * 8;
  for (int k0 = 0; k0 < K; k0 += 32) {
#pragma unroll
    for (int i = 0; i < 2; ++i) {
      const int row0 = w * 32 + i * 16;
      async_copy16(Ag + (size_t)(row0 + r) * ldA + k0 + kk, As + row0 * 32);
      async_copy16(Bg + (size_t)(row0 + r) * ldB + k0 + kk, Bs + row0 * 32);
    }
    __syncthreads();
    s16x8 af[4], bfv[4];
#pragma unroll
    for (int m = 0; m < 4; ++m)
      af[m] = *(const s16x8*)(As + (wr + m * 16 + (lane & 15)) * 32 + (lane >> 4) * 8);
#pragma unroll
    for (int n = 0; n < 4; ++n)
      bfv[n] = *(const s16x8*)(Bs + (wc + n * 16 + (lane & 15)) * 32 + (lane >> 4) * 8);
#pragma unroll
    for (int m = 0; m < 4; ++m)
#pragma unroll
      for (int n = 0; n < 4; ++n)
        acc[m][n] = __builtin_amdgcn_mfma_f32_16x16x32_bf16(af[m], bfv[n], acc[m][n], 0, 0, 0);
    __syncthreads();
  }
}

#define ACC_INIT(acc)                         \
  {                                           \
    const f32x4 z_ = {0.f, 0.f, 0.f, 0.f};    \
    _Pragma("unroll")                         \
    for (int m_ = 0; m_ < 4; ++m_)            \
      _Pragma("unroll")                       \
      for (int n_ = 0; n_ < 4; ++n_) acc[m_][n_] = z_; \
  }

// ---------------- q/k projection (fused z) ----------------
__global__ void __launch_bounds__(256) gemm_proj_qk_kernel(const unsigned short* __restrict__ Xq,
                                                           const unsigned short* __restrict__ Xk,
                                                           const unsigned short* __restrict__ Wbf,
                                                           unsigned short* __restrict__ q_s,
                                                           unsigned short* __restrict__ k_s) {
  __shared__ unsigned short As[4096], Bs[4096];
  f32x4 acc[4][4];
  ACC_INIT(acc);
  const int z = blockIdx.z;
  const unsigned short* X = z ? Xk : Xq;
  const unsigned short* W = Wbf + z * 65536;
  unsigned short* out = z ? k_s : q_s;
  gemm_core_async(X + (size_t)blockIdx.x * 128 * 256, 256,
                  W + (size_t)blockIdx.y * 128 * 256, 256, 256, As, Bs, acc);
  const int tid = threadIdx.x, lane = tid & 63, w = tid >> 6;
  const int wr = (w >> 1) * 64, wc = (w & 1) * 64;
  const int R0 = blockIdx.x * 128 + wr + ((lane >> 4) << 2);
  const int C0 = blockIdx.y * 128 + wc + (lane & 15);
#pragma unroll
  for (int m = 0; m < 4; ++m)
#pragma unroll
    for (int n = 0; n < 4; ++n)
#pragma unroll
      for (int r = 0; r < 4; ++r) {
        int R = R0 + m * 16 + r;          // p = (b*L+l)*16 + hw
        int o = C0 + n * 16;
        int bl = R >> 4, hw = R & 15;
        int b = bl >> 11, l = bl & 2047;
        int head = o >> 5, d = o & 31;
        out[((size_t)(head * 2 + b) * 2048 + l) * 512 + d * 16 + hw] = f2bf(acc[m][n][r]);
      }
}

// (fallback) single projection
__global__ void __launch_bounds__(256) gemm_proj_kernel(const unsigned short* __restrict__ X,
                                                        const unsigned short* __restrict__ W,
                                                        unsigned short* __restrict__ out) {
  __shared__ unsigned short As[4096], Bs[4096];
  f32x4 acc[4][4];
  ACC_INIT(acc);
  gemm_core_async(X + (size_t)blockIdx.x * 128 * 256, 256,
                  W + (size_t)blockIdx.y * 128 * 256, 256, 256, As, Bs, acc);
  const int tid = threadIdx.x, lane = tid & 63, w = tid >> 6;
  const int wr = (w >> 1) * 64, wc = (w & 1) * 64;
  const int R0 = blockIdx.x * 128 + wr + ((lane >> 4) << 2);
  const int C0 = blockIdx.y * 128 + wc + (lane & 15);
#pragma unroll
  for (int m = 0; m < 4; ++m)
#pragma unroll
    for (int n = 0; n < 4; ++n)
#pragma unroll
      for (int r = 0; r < 4; ++r) {
        int R = R0 + m * 16 + r;
        int o = C0 + n * 16;
        int bl = R >> 4, hw = R & 15;
        int b = bl >> 11, l = bl & 2047;
        int head = o >> 5, d = o & 31;
        out[((size_t)(head * 2 + b) * 2048 + l) * 512 + d * 16 + hw] = f2bf(acc[m][n][r]);
      }
}

// ---------------- V projection (transposed): W x X2^T -> v_t[bh][dd][l] ----------------
__global__ void __launch_bounds__(256) gemm_proj_vt_kernel(const unsigned short* __restrict__ W,
                                                           const unsigned short* __restrict__ X2,
                                                           unsigned short* __restrict__ vt) {
  __shared__ unsigned short As[4096], Bs[4096];
  f32x4 acc[4][4];
  ACC_INIT(acc);
  gemm_core_async(W + (size_t)blockIdx.x * 128 * 256, 256,
                  X2 + (size_t)blockIdx.y * 128 * 256, 256, 256, As, Bs, acc);
  const int tid = threadIdx.x, lane = tid & 63, w = tid >> 6;
  const int wr = (w >> 1) * 64, wc = (w & 1) * 64;
  const int R0 = blockIdx.x * 128 + wr + ((lane >> 4) << 2);   // o rows
  const int C0 = blockIdx.y * 128 + wc + (lane & 15);          // p' cols
#pragma unroll
  for (int m = 0; m < 4; ++m)
#pragma unroll
    for (int n = 0; n < 4; ++n)
#pragma unroll
      for (int r = 0; r < 4; ++r) {
        int o = R0 + m * 16 + r;          // channel: head*32 + d
        int p = C0 + n * 16;              // (b*16+hw)*2048 + l
        int head = o >> 5, d = o & 31;
        int b = p >> 15, hw = (p >> 11) & 15, l = p & 2047;
        vt[((size_t)((head * 2 + b) * 512) + d * 16 + hw) * 2048 + l] = f2bf(acc[m][n][r]);
      }
}

// ---------------- normalize: attn = P_bf * inv(rowsum); writes inv[] ----------------
__global__ void __launch_bounds__(256) norm_kernel(const unsigned short* __restrict__ pbf,
                                                   const float* __restrict__ partial,
                                                   float* __restrict__ attn,
                                                   float* __restrict__ inv_buf) {
  __shared__ float sh;
  const int row = blockIdx.x;          // bh*2048 + i
  const int t = threadIdx.x;
  if (t < 32) {
    float v = partial[(size_t)row * 32 + t];
    v += __shfl_xor(v, 1); v += __shfl_xor(v, 2);
    v += __shfl_xor(v, 4); v += __shfl_xor(v, 8); v += __shfl_xor(v, 16);
    if (t == 0) sh = v;
  }
  __syncthreads();
  const float inv = 1.0f / sh;
  if (t == 0) inv_buf[row] = inv;
  s16x8 h = *(const s16x8*)(pbf + (size_t)row * 2048 + t * 8);
  float o[8];
#pragma unroll
  for (int i = 0; i < 8; ++i) o[i] = bf2f((unsigned short)h[i]) * inv;
  float* p = attn + (size_t)row * 2048 + t * 8;
  *(float4*)(p)     = *(float4*)&o[0];
  *(float4*)(p + 4) = *(float4*)&o[4];
}

// ---------------- fallback kernels (R3 path) ----------------
__global__ void __launch_bounds__(256) gemm_score_f32_kernel(const unsigned short* __restrict__ q,
                                                             const unsigned short* __restrict__ k,
                                                             float* __restrict__ attn) {
  __shared__ unsigned short As[4096], Bs[4096];
  f32x4 acc[4][4];
  ACC_INIT(acc);
  const int bh = blockIdx.z;
  gemm_core_async(q + ((size_t)bh * 2048 + blockIdx.x * 128) * 512, 512,
                  k + ((size_t)bh * 2048 + blockIdx.y * 128) * 512, 512, 512, As, Bs, acc);
  const int tid = threadIdx.x, lane = tid & 63, w = tid >> 6;
  const int wr = (w >> 1) * 64, wc = (w & 1) * 64;
  float* O = attn + (size_t)bh * 4194304;
  const float scale = 0.17677669529663687f;
  const int R0 = blockIdx.x * 128 + wr + ((lane >> 4) << 2);
  const int C0 = blockIdx.y * 128 + wc + (lane & 15);
#pragma unroll
  for (int m = 0; m < 4; ++m)
#pragma unroll
    for (int n = 0; n < 4; ++n)
#pragma unroll
      for (int r = 0; r < 4; ++r)
        O[(size_t)(R0 + m * 16 + r) * 2048 + (C0 + n * 16)] = acc[m][n][r] * scale;
}

__global__ void __launch_bounds__(256) softmax_kernel(float* __restrict__ attn) {
  __shared__ float red[4];
  float* p = attn + (size_t)blockIdx.x * 2048;
  const int t = threadIdx.x;
  float4 v0 = *(const float4*)(p + t * 8);
  float4 v1 = *(const float4*)(p + t * 8 + 4);
  float mx = fmaxf(fmaxf(fmaxf(v0.x, v0.y), fmaxf(v0.z, v0.w)),
                   fmaxf(fmaxf(v1.x, v1.y), fmaxf(v1.z, v1.w)));
#pragma unroll
  for (int off = 32; off; off >>= 1) mx = fmaxf(mx, __shfl_xor(mx, off));
  if ((t & 63) == 0) red[t >> 6] = mx;
  __syncthreads();
  mx = fmaxf(fmaxf(red[0], red[1]), fmaxf(red[2], red[3]));
  __syncthreads();
  float e[8];
  e[0] = __expf(v0.x - mx); e[1] = __expf(v0.y - mx);
  e[2] = __expf(v0.z - mx); e[3] = __expf(v0.w - mx);
  e[4] = __expf(v1.x - mx); e[5] = __expf(v1.y - mx);
  e[6] = __expf(v1.z - mx); e[7] = __expf(v1.w - mx);
  float s = ((e[0] + e[1]) + (e[2] + e[3])) + ((e[4] + e[5]) + (e[6] + e[7]));
#pragma unroll
  for (int off = 32; off; off >>= 1) s += __shfl_xor(s, off);
  if ((t & 63) == 0) red[t >> 6] = s;
  __syncthreads();
  s = red[0] + red[1] + red[2] + red[3];
  const float inv = 1.0f / s;
  float4 o0 = {e[0] * inv, e[1] * inv, e[2] * inv, e[3] * inv};
  float4 o1 = {e[4] * inv, e[5] * inv, e[6] * inv, e[7] * inv};
  *(float4*)(p + t * 8) = o0;
  *(float4*)(p + t * 8 + 4) = o1;
}

__global__ void __launch_bounds__(256) transpose_v_kernel(const unsigned short* __restrict__ vs,
                                                          unsigned short* __restrict__ vt) {
  __shared__ unsigned short tile[64][65];
  const int bh = blockIdx.z;
  const int j0 = blockIdx.x * 64, d0 = blockIdx.y * 64;
  const unsigned short* src = vs + (size_t)bh * 2048 * 512;
  unsigned short* dst = vt + (size_t)bh * 512 * 2048;
  const int t = threadIdx.x;
#pragma unroll
  for (int i = 0; i < 16; ++i) {
    int e = t * 16 + i;
    int r = e >> 6, c = e & 63;
    tile[r][c] = src[(size_t)(j0 + r) * 512 + d0 + c];
  }
  __syncthreads();
#pragma unroll
  for (int i = 0; i < 16; ++i) {
    int e = t * 16 + i;
    int r = e >> 6, c = e & 63;
    dst[(size_t)(d0 + r) * 2048 + j0 + c] = tile[c][r];
  }
}

__global__ void __launch_bounds__(256) gemm_ctx_f32_kernel(const float* __restrict__ attn,
                                                           const unsigned short* __restrict__ vt,
                                                           float* __restrict__ outc) {
  __shared__ unsigned short As[4096], Bs[4096];
  f32x4 acc[4][4];
  ACC_INIT(acc);
  const int tid = threadIdx.x, lane = tid & 63, w = tid >> 6;
  const int wr = (w >> 1) * 64, wc = (w & 1) * 64;
  const int bh = blockIdx.z;
  const float* Ag = attn + (size_t)bh * 4194304 + (size_t)blockIdx.x * 128 * 2048;
  const unsigned short* Bg = vt + (size_t)bh * 1048576 + (size_t)blockIdx.y * 128 * 2048;
  const int r = lane >> 2, kk = (lane & 3) * 8;
  const int arow = tid >> 1, acol = (tid & 1) * 16;
  for (int k0 = 0; k0 < 2048; k0 += 32) {
#pragma unroll
    for (int i = 0; i < 2; ++i) {
      const int row0 = w * 32 + i * 16;
      async_copy16(Bg + (size_t)(row0 + r) * 2048 + k0 + kk, Bs + row0 * 32);
    }
    {
      const float* sp = Ag + (size_t)arow * 2048 + k0 + acol;
      float4 f0 = *(const float4*)(sp);
      float4 f1 = *(const float4*)(sp + 4);
      float4 f2 = *(const float4*)(sp + 8);
      float4 f3 = *(const float4*)(sp + 12);
      s16x8 h0, h1;
      h0[0] = (short)f2bf(f0.x); h0[1] = (short)f2bf(f0.y);
      h0[2] = (short)f2bf(f0.z); h0[3] = (short)f2bf(f0.w);
      h0[4] = (short)f2bf(f1.x); h0[5] = (short)f2bf(f1.y);
      h0[6] = (short)f2bf(f1.z); h0[7] = (short)f2bf(f1.w);
      h1[0] = (short)f2bf(f2.x); h1[1] = (short)f2bf(f2.y);
      h1[2] = (short)f2bf(f2.z); h1[3] = (short)f2bf(f2.w);
      h1[4] = (short)f2bf(f3.x); h1[5] = (short)f2bf(f3.y);
      h1[6] = (short)f2bf(f3.z); h1[7] = (short)f2bf(f3.w);
      *(s16x8*)(As + arow * 32 + acol) = h0;
      *(s16x8*)(As + arow * 32 + acol + 8) = h1;
    }
    __syncthreads();
    s16x8 af[4], bfv[4];
#pragma unroll
    for (int m = 0; m < 4; ++m)
      af[m] = *(const s16x8*)(As + (wr + m * 16 + (lane & 15)) * 32 + (lane >> 4) * 8);
#pragma unroll
    for (int n = 0; n < 4; ++n)
      bfv[n] = *(const s16x8*)(Bs + (wc + n * 16 + (lane & 15)) * 32 + (lane >> 4) * 8);
#pragma unroll
    for (int m = 0; m < 4; ++m)
#pragma unroll
      for (int n = 0; n < 4; ++n)
        acc[m][n] = __builtin_amdgcn_mfma_f32_16x16x32_bf16(af[m], bfv[n], acc[m][n], 0, 0, 0);
    __syncthreads();
  }
  const int b = bh & 1, head = bh >> 1;
  const int R0 = blockIdx.x * 128 + wr + ((lane >> 4) << 2);
  const int C0 = blockIdx.y * 128 + wc + (lane & 15);
#pragma unroll
  for (int m = 0; m < 4; ++m)
#pragma unroll
    for (int n = 0; n < 4; ++n)
#pragma unroll
      for (int r2 = 0; r2 < 4; ++r2) {
        int R = R0 + m * 16 + r2;
        int dd = C0 + n * 16;
        outc[((size_t)(b * 2048 + R) * 256 + head * 32 + (dd >> 4)) * 16 + (dd & 15)] =
            acc[m][n][r2];
      }
}

extern "C" void kernel_launch(void* const* d_in, const int* in_sizes, int n_in,
                              void* d_out, int out_size, void* d_ws, size_t ws_size,
                              hipStream_t stream) {
  const float* query = (const float*)d_in[0];
  const float* key   = (const float*)d_in[1];
  const float* value = (const float*)d_in[2];
  const float* Wq    = (const float*)d_in[3];
  const float* Wk    = (const float*)d_in[4];
  const float* Wv    = (const float*)d_in[5];

  float* out_ctx  = (float*)d_out;
  float* out_attn = (float*)d_out + 16777216;

  unsigned short* X2   = (unsigned short*)d_ws;
  unsigned short* q_s  = X2 + 16777216;
  unsigned short* k_s  = q_s + 16777216;
  unsigned short* v_t  = k_s + 16777216;
  unsigned short* Wbf  = v_t + 16777216;        // 196,608 shorts
  unsigned short* P_bf = Wbf + 196608;          // 67,108,864 shorts
  float* partial = (float*)(P_bf + 67108864);   // 1,048,576 floats
  float* inv_buf = partial + 1048576;           // 32,768 floats

  unsigned short* Xq = P_bf;                    // aliases (dead before score writes P_bf)
  unsigned short* Xk = P_bf + 16777216;

  const bool fused = ws_size >= (size_t)273154048;

  prep_w_kernel<<<768, 256, 0, stream>>>(Wq, Wk, Wv, Wbf);

  if (fused) {
    prep_all_kernel<<<dim3(4096, 3), 256, 0, stream>>>(query, key, value, Xq, Xk, X2);
    gemm_proj_qk_kernel<<<dim3(512, 2, 2), 256, 0, stream>>>(Xq, Xk, Wbf, q_s, k_s);
    gemm_proj_vt_kernel<<<dim3(2, 512), 256, 0, stream>>>(Wbf + 131072, X2, v_t);
    gemm_score256_kernel<<<dim3(8, 8, 16), 512, 0, stream>>>(q_s, k_s, P_bf, partial);
    norm_kernel<<<32768, 256, 0, stream>>>(P_bf, partial, out_attn, inv_buf);
    gemm_ctx256_kernel<<<dim3(8, 2, 16), 512, 0, stream>>>(P_bf, v_t, inv_buf, out_ctx);
  } else {
    prep_x_kernel<<<4096, 256, 0, stream>>>(query, X2);
    gemm_proj_kernel<<<dim3(512, 2), 256, 0, stream>>>(X2, Wbf, q_s);
    prep_x_kernel<<<4096, 256, 0, stream>>>(key, X2);
    gemm_proj_kernel<<<dim3(512, 2), 256, 0, stream>>>(X2, Wbf + 65536, k_s);
    prep_x_kernel<<<4096, 256, 0, stream>>>(value, X2);
    gemm_proj_kernel<<<dim3(512, 2), 256, 0, stream>>>(X2, Wbf + 131072, v_t);  // v_s layout
    gemm_score_f32_kernel<<<dim3(16, 16, 16), 256, 0, stream>>>(q_s, k_s, out_attn);
    softmax_kernel<<<32768, 256, 0, stream>>>(out_attn);
    transpose_v_kernel<<<dim3(32, 8, 16), 256, 0, stream>>>(v_t, X2);           // X2 becomes v_t
    gemm_ctx_f32_kernel<<<dim3(16, 4, 16), 256, 0, stream>>>(out_attn, X2, out_ctx);
  }
}